// Round 1
// baseline (1865.488 us; speedup 1.0000x reference)
//
#include <hip/hip_runtime.h>
#include <cstddef>

// Problem constants
constexpr int B_ = 32;
constexpr int C_ = 512;
constexpr int N_ = 512;
constexpr int H_ = 8;
constexpr int DH_ = 64;      // head dim
constexpr int FH_ = 1024;    // ffn hidden
constexpr float BN_EPS_ = 1e-5f;

enum { EPI_NONE = 0, EPI_GELU = 1, EPI_BN = 2 };

// ---------------------------------------------------------------------------
// Generic pointwise-conv GEMM: Y[b][o][n] = sum_c W[o][c] * X[b][c][n] + bias[o]
// Block tile 64(o) x 64(n), 256 threads, each thread 4x4, K-step 16.
// Epilogues: none | exact GELU | residual-add + eval BatchNorm.
// ---------------------------------------------------------------------------
template <int EPI>
__global__ __launch_bounds__(256)
void gemm_pw(const float* __restrict__ W, const float* __restrict__ X,
             const float* __restrict__ bias, float* __restrict__ Y,
             int O, int K,
             const float* __restrict__ resid,
             const float* __restrict__ bng, const float* __restrict__ bnb,
             const float* __restrict__ bnm, const float* __restrict__ bnv)
{
    const int b  = blockIdx.z;
    const int o0 = blockIdx.x * 64;
    const int n0 = blockIdx.y * 64;

    const float* Xb = X + (size_t)b * K * N_;
    float*       Yb = Y + (size_t)b * O * N_;

    __shared__ float sW[16][65];  // [k][o]
    __shared__ float sX[16][65];  // [k][n]

    const int t  = threadIdx.x;
    const int tx = t % 16;        // n-group
    const int ty = t / 16;        // o-group

    float acc[4][4] = {};

    for (int k0 = 0; k0 < K; k0 += 16) {
        {
            // W tile: 64 o x 16 k
            int k = t % 16, o = t / 16;
#pragma unroll
            for (int i = 0; i < 4; ++i)
                sW[k][o + i * 16] = W[(size_t)(o0 + o + i * 16) * K + k0 + k];
            // X tile: 16 k x 64 n (coalesced rows)
            int j = t % 64, kk = t / 64;
#pragma unroll
            for (int i = 0; i < 4; ++i)
                sX[kk + i * 4][j] = Xb[(size_t)(k0 + kk + i * 4) * N_ + n0 + j];
        }
        __syncthreads();

#pragma unroll
        for (int k = 0; k < 16; ++k) {
            float wv[4], xv[4];
#pragma unroll
            for (int i = 0; i < 4; ++i) wv[i] = sW[k][ty * 4 + i];
#pragma unroll
            for (int j = 0; j < 4; ++j) xv[j] = sX[k][tx * 4 + j];
#pragma unroll
            for (int i = 0; i < 4; ++i)
#pragma unroll
                for (int j = 0; j < 4; ++j)
                    acc[i][j] += wv[i] * xv[j];
        }
        __syncthreads();
    }

#pragma unroll
    for (int i = 0; i < 4; ++i) {
        const int o = o0 + ty * 4 + i;
        const float bv = bias[o];
        float sc = 0.f, sh = 0.f;
        if (EPI == EPI_BN) {
            const float inv = rsqrtf(bnv[o] + BN_EPS_);
            sc = bng[o] * inv;
            sh = bnb[o] - bnm[o] * sc;
        }
#pragma unroll
        for (int j = 0; j < 4; ++j) {
            const int n = n0 + tx * 4 + j;
            float v = acc[i][j] + bv;
            const size_t idx = (size_t)o * N_ + n;
            if (EPI == EPI_GELU) {
                v = 0.5f * v * (1.0f + erff(v * 0.70710678118654752f));
            } else if (EPI == EPI_BN) {
                const float r = resid[(size_t)b * O * N_ + idx];
                v = (v + r) * sc + sh;
            }
            Yb[idx] = v;
        }
    }
}

// ---------------------------------------------------------------------------
// Attention: per block handles (b, h, 16 query rows).
// qkv layout: [B][3C][N]; q channel = h*64+d, k at +512, v at +1024.
// scores[r][m] = scale * sum_d q[d][n0+r]*k[d][m] + rel[(m-n+511)*8+h]
// softmax over m, then out[r][d] = (1/sum) * sum_m p[r][m] * v[d][m]
// ---------------------------------------------------------------------------
__global__ __launch_bounds__(256)
void attn_kernel(const float* __restrict__ qkv, const float* __restrict__ rel,
                 float* __restrict__ out)
{
    const int n0 = blockIdx.x * 16;
    const int h  = blockIdx.y;
    const int b  = blockIdx.z;
    const int t  = threadIdx.x;

    __shared__ float sQ[16][65];     // [r][d]
    __shared__ float sS[16][512];    // scores / probabilities
    __shared__ float sV[32][65];     // [mm][d] staged V tile
    __shared__ float sInv[16];       // 1/rowsum

    const float* qbase = qkv + ((size_t)b * (3 * C_) + h * DH_) * N_;
    const float* kbase = qkv + ((size_t)b * (3 * C_) + C_ + h * DH_) * N_;
    const float* vbase = qkv + ((size_t)b * (3 * C_) + 2 * C_ + h * DH_) * N_;

    // ---- load Q tile ----
    {
        int r = t % 16;
        int d0 = t / 16;
#pragma unroll
        for (int i = 0; i < 4; ++i) {
            int d = d0 + i * 16;
            sQ[r][d] = qbase[(size_t)d * N_ + n0 + r];
        }
    }
    __syncthreads();

    // ---- phase 1: scores ----
#pragma unroll 1
    for (int mt = 0; mt < 2; ++mt) {
        const int m = mt * 256 + t;
        float acc[16];
#pragma unroll
        for (int r = 0; r < 16; ++r) acc[r] = 0.f;
        for (int d = 0; d < DH_; ++d) {
            const float kv = kbase[(size_t)d * N_ + m];
#pragma unroll
            for (int r = 0; r < 16; ++r) acc[r] += sQ[r][d] * kv;
        }
#pragma unroll
        for (int r = 0; r < 16; ++r) {
            int idx = m - (n0 + r) + 511;           // always in [0,1022]
            idx = max(0, min(1022, idx));
            sS[r][m] = acc[r] * 0.125f + rel[idx * H_ + h];
        }
    }
    __syncthreads();

    // ---- phase 2: softmax (16 threads per row) ----
    {
        const int r = t / 16;
        const int l = t % 16;
        float mx = -1e30f;
        for (int m = l; m < 512; m += 16) mx = fmaxf(mx, sS[r][m]);
#pragma unroll
        for (int off = 8; off > 0; off >>= 1) mx = fmaxf(mx, __shfl_xor(mx, off, 64));
        float sum = 0.f;
        for (int m = l; m < 512; m += 16) {
            const float e = __expf(sS[r][m] - mx);
            sS[r][m] = e;
            sum += e;
        }
#pragma unroll
        for (int off = 8; off > 0; off >>= 1) sum += __shfl_xor(sum, off, 64);
        if (l == 0) sInv[r] = 1.0f / sum;
    }
    __syncthreads();

    // ---- phase 3: out = P @ V, staged V tiles of 32 m ----
    const int d  = t % 64;
    const int r0 = t / 64;                      // rows r0, r0+4, r0+8, r0+12
    float acc[4] = {0.f, 0.f, 0.f, 0.f};

    for (int mt = 0; mt < 16; ++mt) {
        const int m0 = mt * 32;
        {
            int mm = t % 32, dd = t / 32;       // dd in 0..7
#pragma unroll
            for (int i = 0; i < 8; ++i)
                sV[mm][dd + i * 8] = vbase[(size_t)(dd + i * 8) * N_ + m0 + mm];
        }
        __syncthreads();
#pragma unroll 4
        for (int mm = 0; mm < 32; ++mm) {
            const float vv = sV[mm][d];
#pragma unroll
            for (int i = 0; i < 4; ++i)
                acc[i] += sS[r0 + 4 * i][m0 + mm] * vv;
        }
        __syncthreads();
    }

    float* obase = out + ((size_t)b * C_ + h * DH_ + d) * N_ + n0;
#pragma unroll
    for (int i = 0; i < 4; ++i) {
        const int r = r0 + 4 * i;
        obase[r] = acc[i] * sInv[r];
    }
}

// ---------------------------------------------------------------------------
extern "C" void kernel_launch(void* const* d_in, const int* in_sizes, int n_in,
                              void* d_out, int out_size, void* d_ws, size_t ws_size,
                              hipStream_t stream)
{
    const float* x      = (const float*)d_in[0];
    const float* qkv_w  = (const float*)d_in[1];
    const float* qkv_b  = (const float*)d_in[2];
    const float* out_w  = (const float*)d_in[3];
    const float* out_b  = (const float*)d_in[4];
    const float* rel    = (const float*)d_in[5];
    const float* bn1_g  = (const float*)d_in[6];
    const float* bn1_b  = (const float*)d_in[7];
    const float* bn1_m  = (const float*)d_in[8];
    const float* bn1_v  = (const float*)d_in[9];
    const float* ffn1_w = (const float*)d_in[10];
    const float* ffn1_b = (const float*)d_in[11];
    const float* ffn2_w = (const float*)d_in[12];
    const float* ffn2_b = (const float*)d_in[13];
    const float* bn2_g  = (const float*)d_in[14];
    const float* bn2_b  = (const float*)d_in[15];
    const float* bn2_m  = (const float*)d_in[16];
    const float* bn2_v  = (const float*)d_in[17];

    float* out = (float*)d_out;
    float* ws  = (float*)d_ws;

    float* qkv  = ws;                                   // 32*1536*512
    float* attn = qkv + (size_t)B_ * 3 * C_ * N_;       // 32*512*512
    float* f1   = attn + (size_t)B_ * C_ * N_;          // 32*1024*512

    const dim3 blk(256);

    // 1) qkv projection: [1536,512] x [512,512] per batch
    gemm_pw<EPI_NONE><<<dim3(3 * C_ / 64, N_ / 64, B_), blk, 0, stream>>>(
        qkv_w, x, qkv_b, qkv, 3 * C_, C_, nullptr, nullptr, nullptr, nullptr, nullptr);

    // 2) attention
    attn_kernel<<<dim3(N_ / 16, H_, B_), blk, 0, stream>>>(qkv, rel, attn);

    // 3) out projection + residual(x) + BN1 -> h (in d_out)
    gemm_pw<EPI_BN><<<dim3(C_ / 64, N_ / 64, B_), blk, 0, stream>>>(
        out_w, attn, out_b, out, C_, C_, x, bn1_g, bn1_b, bn1_m, bn1_v);

    // 4) ffn1 + exact GELU -> f1
    gemm_pw<EPI_GELU><<<dim3(FH_ / 64, N_ / 64, B_), blk, 0, stream>>>(
        ffn1_w, out, ffn1_b, f1, FH_, C_, nullptr, nullptr, nullptr, nullptr, nullptr);

    // 5) ffn2 + residual(h) + BN2 -> d_out
    gemm_pw<EPI_BN><<<dim3(C_ / 64, N_ / 64, B_), blk, 0, stream>>>(
        ffn2_w, f1, ffn2_b, out, C_, FH_, out, bn2_g, bn2_b, bn2_m, bn2_v);
}

// Round 4
// 241.214 us; speedup vs baseline: 7.7338x; 7.7338x over previous
//
#include <hip/hip_runtime.h>
#include <cstddef>
#include <cstdint>

constexpr int B_ = 32;
constexpr int C_ = 512;
constexpr int N_ = 512;
constexpr int H_ = 8;
constexpr int FH_ = 1024;
constexpr float BN_EPS_ = 1e-5f;

typedef __attribute__((ext_vector_type(8))) short bf16x8;
typedef __attribute__((ext_vector_type(4))) short s16x4;
typedef __attribute__((ext_vector_type(4))) float f32x4;

enum { EPI_QKV = 0, EPI_BN1 = 1, EPI_GELU = 2, EPI_BN2 = 3 };

__device__ inline void gload_lds16(const void* g, void* l) {
    __builtin_amdgcn_global_load_lds(
        (const __attribute__((address_space(1))) void*)g,
        (__attribute__((address_space(3))) void*)l, 16, 0, 0);
}

__device__ inline short f2bf(float f) {
    union { float f; uint32_t u; } v; v.f = f;
    uint32_t r = v.u + 0x7fffu + ((v.u >> 16) & 1u);
    return (short)(r >> 16);
}

// ---------------------------------------------------------------------------
// fp32 -> bf16 elementwise (weights)
// ---------------------------------------------------------------------------
__global__ __launch_bounds__(256) void cvt_bf16_k(const float* __restrict__ s,
                                                  short* __restrict__ d, int n4)
{
    int i = blockIdx.x * 256 + threadIdx.x;
    if (i < n4) {
        f32x4 v = *(const f32x4*)&s[(size_t)i * 4];
        s16x4 o;
        o[0] = f2bf(v[0]); o[1] = f2bf(v[1]); o[2] = f2bf(v[2]); o[3] = f2bf(v[3]);
        *(s16x4*)&d[(size_t)i * 4] = o;
    }
}

// ---------------------------------------------------------------------------
// x [B][C][N] fp32 -> xT [B][N][C] bf16
// ---------------------------------------------------------------------------
__global__ __launch_bounds__(256) void transpose_x(const float* __restrict__ x,
                                                   short* __restrict__ xT)
{
    __shared__ __align__(16) float s[64][65];
    const int b = blockIdx.z, c0 = blockIdx.x * 64, n0 = blockIdx.y * 64;
    const int t = threadIdx.x;
    const float* xb = x + ((size_t)b * C_ + c0) * N_ + n0;
    {
        int nl = t & 63, cl = t >> 6;
#pragma unroll
        for (int i = 0; i < 16; ++i)
            s[cl + i * 4][nl] = xb[(size_t)(cl + i * 4) * N_ + nl];
    }
    __syncthreads();
    short* xTb = xT + ((size_t)b * N_ + n0) * C_ + c0;
    {
        int cl = t & 63, nl = t >> 6;
#pragma unroll
        for (int i = 0; i < 16; ++i)
            xTb[(size_t)(nl + i * 4) * C_ + cl] = f2bf(s[cl][nl + i * 4]);
    }
}

// ---------------------------------------------------------------------------
// MFMA GEMM: Y[b][n][o] = sum_c A[b][n][c] * W[o][c]  (+ epilogue)
// 128x128 tile, BK=32, 256 threads (4 waves, 2x2), 16x16x32 bf16 MFMA.
// ---------------------------------------------------------------------------
template <int EPI, int KD, int OSTR>
__global__ __launch_bounds__(256) void gemm_mfma(
    const short* __restrict__ A, const short* __restrict__ W,
    const float* __restrict__ bias,
    short* __restrict__ Yb, short* __restrict__ Yv, float* __restrict__ Yf,
    const float* __restrict__ res,
    const float* __restrict__ g, const float* __restrict__ bt,
    const float* __restrict__ mn, const float* __restrict__ vr)
{
    const int b  = blockIdx.z;
    const int o0 = blockIdx.x * 128;
    const int n0 = blockIdx.y * 128;
    const short* Ab = A + (size_t)b * 512 * KD;

    __shared__ __align__(16) short As[128 * 32];
    __shared__ __align__(16) short Bs[128 * 32];

    const int t = threadIdx.x;
    const int lane = t & 63, w = t >> 6;
    const int l15 = lane & 15, lg = lane >> 4;
    const int wr = w >> 1, wc = w & 1;

    const f32x4 zero4 = {0.f, 0.f, 0.f, 0.f};
    f32x4 acc[4][4];
#pragma unroll
    for (int i = 0; i < 4; ++i)
#pragma unroll
        for (int j = 0; j < 4; ++j) acc[i][j] = zero4;

    const int r0 = t >> 2;            // staging row (0..63), +64 for 2nd instr
    const int kb = (t & 3) * 8;       // staging k offset

    for (int k0 = 0; k0 < KD; k0 += 32) {
        gload_lds16(Ab + (size_t)(n0 + r0) * KD + k0 + kb,       &As[w * 512]);
        gload_lds16(Ab + (size_t)(n0 + r0 + 64) * KD + k0 + kb,  &As[w * 512 + 2048]);
        gload_lds16(W  + (size_t)(o0 + r0) * KD + k0 + kb,       &Bs[w * 512]);
        gload_lds16(W  + (size_t)(o0 + r0 + 64) * KD + k0 + kb,  &Bs[w * 512 + 2048]);
        __syncthreads();

        bf16x8 af[4], bf[4];
#pragma unroll
        for (int mi = 0; mi < 4; ++mi)
            af[mi] = *(const bf16x8*)&As[(wr * 64 + mi * 16 + l15) * 32 + lg * 8];
#pragma unroll
        for (int ni = 0; ni < 4; ++ni)
            bf[ni] = *(const bf16x8*)&Bs[(wc * 64 + ni * 16 + l15) * 32 + lg * 8];
#pragma unroll
        for (int mi = 0; mi < 4; ++mi)
#pragma unroll
            for (int ni = 0; ni < 4; ++ni)
                acc[mi][ni] = __builtin_amdgcn_mfma_f32_16x16x32_bf16(
                    af[mi], bf[ni], acc[mi][ni], 0, 0, 0);
        __syncthreads();
    }

    // epilogue
#pragma unroll
    for (int mi = 0; mi < 4; ++mi) {
        const int nb = n0 + wr * 64 + mi * 16 + lg * 4;   // rows nb..nb+3
#pragma unroll
        for (int ni = 0; ni < 4; ++ni) {
            const int o = o0 + wc * 64 + ni * 16 + l15;
            const float bv = bias[o];
            f32x4 v = acc[mi][ni];
            if constexpr (EPI == EPI_QKV) {
                if (o0 < 1024) {
#pragma unroll
                    for (int r = 0; r < 4; ++r)
                        Yb[((size_t)b * 512 + nb + r) * 1024 + o] = f2bf(v[r] + bv);
                } else {
                    s16x4 pk;
#pragma unroll
                    for (int r = 0; r < 4; ++r) pk[r] = f2bf(v[r] + bv);
                    *(s16x4*)&Yv[((size_t)b * 512 + (o - 1024)) * 512 + nb] = pk;
                }
            } else if constexpr (EPI == EPI_BN1) {
                const float sc = g[o] * rsqrtf(vr[o] + BN_EPS_);
                const float sh = bt[o] - mn[o] * sc;
                f32x4 rr = *(const f32x4*)&res[((size_t)b * 512 + o) * 512 + nb];
#pragma unroll
                for (int r = 0; r < 4; ++r) {
                    float val = (v[r] + bv + rr[r]) * sc + sh;
                    Yb[((size_t)b * 512 + nb + r) * 512 + o] = f2bf(val);
                    Yf[((size_t)b * 512 + nb + r) * 512 + o] = val;
                }
            } else if constexpr (EPI == EPI_GELU) {
#pragma unroll
                for (int r = 0; r < 4; ++r) {
                    float val = v[r] + bv;
                    val = 0.5f * val * (1.0f + erff(val * 0.70710678118654752f));
                    Yb[((size_t)b * 512 + nb + r) * OSTR + o] = f2bf(val);
                }
            } else { // EPI_BN2 -> final fp32 out [b][o][n]
                const float sc = g[o] * rsqrtf(vr[o] + BN_EPS_);
                const float sh = bt[o] - mn[o] * sc;
                f32x4 ov;
#pragma unroll
                for (int r = 0; r < 4; ++r) {
                    float hres = res[((size_t)b * 512 + nb + r) * 512 + o];
                    ov[r] = (v[r] + bv + hres) * sc + sh;
                }
                *(f32x4*)&Yf[((size_t)b * 512 + o) * 512 + nb] = ov;
            }
        }
    }
}

// ---------------------------------------------------------------------------
// Attention (flash-style, MFMA). Block: (b, h, 64 q-rows), 4 waves x 16 rows.
// qkT [B][512][1024] bf16 (q ch 0..511, k ch 512..1023), vT [B][512][512] bf16.
// m-tiles of 128; K/V staged in LDS (XOR-swizzled via pre-swizzled global src).
// ---------------------------------------------------------------------------
__global__ __launch_bounds__(256) void attn_mfma(
    const short* __restrict__ qkT, const short* __restrict__ vT,
    const float* __restrict__ rel, short* __restrict__ attnT)
{
    const int n0 = blockIdx.x * 64;
    const int h  = blockIdx.y;
    const int b  = blockIdx.z;
    const int t  = threadIdx.x;
    const int lane = t & 63, w = t >> 6;
    const int l15 = lane & 15, lg = lane >> 4;

    __shared__ __align__(16) short Qs[64 * 64];
    __shared__ __align__(16) short Ks[128 * 64];
    __shared__ __align__(16) short Vs[64 * 128];
    __shared__ __align__(16) short Ps[4][16 * 128];
    __shared__ __align__(16) float relh[1024];

    const short* qb = qkT + (size_t)b * 512 * 1024;
    const short* vb = vT + (size_t)b * 512 * 512;

    for (int i = t; i < 1023; i += 256) relh[i] = rel[i * H_ + h];

    // stage Q (swizzled 16B blocks within each 64-elem row)
#pragma unroll
    for (int i = 0; i < 2; ++i) {
        int fl = t * 8 + i * 2048;
        int r = fl >> 6;
        int blk = (fl >> 3) & 7;
        int d = ((blk ^ (r & 7)) << 3);
        gload_lds16(qb + (size_t)(n0 + r) * 1024 + h * 64 + d, &Qs[w * 512 + i * 2048]);
    }
    __syncthreads();

    const f32x4 zero4 = {0.f, 0.f, 0.f, 0.f};
    f32x4 acc_o[4];
#pragma unroll
    for (int dj = 0; dj < 4; ++dj) acc_o[dj] = zero4;
    float rmax[4], rsum[4];
#pragma unroll
    for (int r = 0; r < 4; ++r) { rmax[r] = -3e38f; rsum[r] = 0.f; }

    for (int m0 = 0; m0 < 512; m0 += 128) {
        // stage K [128 m][64 d]
#pragma unroll
        for (int i = 0; i < 4; ++i) {
            int fl = t * 8 + i * 2048;
            int r = fl >> 6;
            int blk = (fl >> 3) & 7;
            int d = ((blk ^ (r & 7)) << 3);
            gload_lds16(qb + (size_t)(m0 + r) * 1024 + 512 + h * 64 + d,
                        &Ks[w * 512 + i * 2048]);
        }
        // stage V^T [64 d][128 m]
#pragma unroll
        for (int i = 0; i < 4; ++i) {
            int fl = t * 8 + i * 2048;
            int r = fl >> 7;
            int blk = (fl >> 3) & 15;
            int m = ((blk ^ (r & 7)) << 3);
            gload_lds16(vb + (size_t)(h * 64 + r) * 512 + m0 + m,
                        &Vs[w * 512 + i * 2048]);
        }
        __syncthreads();

        // QK^T : S rows = w*16 + lg*4+reg, cols = m0 + ni*16 + l15
        f32x4 s[8];
        {
            bf16x8 aq[2];
#pragma unroll
            for (int kk = 0; kk < 2; ++kk) {
                int qr = w * 16 + l15;
                aq[kk] = *(const bf16x8*)&Qs[qr * 64 + (((kk * 4 + lg) ^ (qr & 7)) << 3)];
            }
#pragma unroll
            for (int ni = 0; ni < 8; ++ni) {
                int mr = ni * 16 + l15;
                f32x4 a = zero4;
#pragma unroll
                for (int kk = 0; kk < 2; ++kk) {
                    bf16x8 bk = *(const bf16x8*)&Ks[mr * 64 + (((kk * 4 + lg) ^ (mr & 7)) << 3)];
                    a = __builtin_amdgcn_mfma_f32_16x16x32_bf16(aq[kk], bk, a, 0, 0, 0);
                }
                s[ni] = a;
            }
        }

        // bias + online softmax
        float scale[4];
#pragma unroll
        for (int reg = 0; reg < 4; ++reg) {
            const int nglob = n0 + w * 16 + lg * 4 + reg;
            float tmax = -3e38f;
#pragma unroll
            for (int ni = 0; ni < 8; ++ni) {
                int mglob = m0 + ni * 16 + l15;
                float sv = s[ni][reg] * 0.125f + relh[mglob - nglob + 511];
                s[ni][reg] = sv;
                tmax = fmaxf(tmax, sv);
            }
            tmax = fmaxf(tmax, __shfl_xor(tmax, 1));
            tmax = fmaxf(tmax, __shfl_xor(tmax, 2));
            tmax = fmaxf(tmax, __shfl_xor(tmax, 4));
            tmax = fmaxf(tmax, __shfl_xor(tmax, 8));
            const float nm = fmaxf(rmax[reg], tmax);
            scale[reg] = __expf(rmax[reg] - nm);
            rmax[reg] = nm;
            float ts = 0.f;
#pragma unroll
            for (int ni = 0; ni < 8; ++ni) {
                float p = __expf(s[ni][reg] - nm);
                s[ni][reg] = p;
                ts += p;
            }
            ts += __shfl_xor(ts, 1); ts += __shfl_xor(ts, 2);
            ts += __shfl_xor(ts, 4); ts += __shfl_xor(ts, 8);
            rsum[reg] = rsum[reg] * scale[reg] + ts;
        }
#pragma unroll
        for (int dj = 0; dj < 4; ++dj)
#pragma unroll
            for (int reg = 0; reg < 4; ++reg) acc_o[dj][reg] *= scale[reg];

        // write P to LDS (bf16, swizzled)
#pragma unroll
        for (int ni = 0; ni < 8; ++ni)
#pragma unroll
            for (int reg = 0; reg < 4; ++reg) {
                int rl = lg * 4 + reg;
                int m = ni * 16 + l15;
                int blk = (m >> 3) ^ (rl & 7);
                Ps[w][rl * 128 + (blk << 3) + (m & 7)] = f2bf(s[ni][reg]);
            }
        __syncthreads();

        // PV
#pragma unroll
        for (int kk = 0; kk < 4; ++kk) {
            bf16x8 ap = *(const bf16x8*)&Ps[w][l15 * 128 + (((kk * 4 + lg) ^ (l15 & 7)) << 3)];
#pragma unroll
            for (int dj = 0; dj < 4; ++dj) {
                int dr = dj * 16 + l15;
                bf16x8 bv = *(const bf16x8*)&Vs[dr * 128 + (((kk * 4 + lg) ^ (dr & 7)) << 3)];
                acc_o[dj] = __builtin_amdgcn_mfma_f32_16x16x32_bf16(ap, bv, acc_o[dj], 0, 0, 0);
            }
        }
        __syncthreads();
    }

    short* ob = attnT + (size_t)b * 512 * 512;
#pragma unroll
    for (int dj = 0; dj < 4; ++dj)
#pragma unroll
        for (int reg = 0; reg < 4; ++reg) {
            int nglob = n0 + w * 16 + lg * 4 + reg;
            ob[(size_t)nglob * 512 + h * 64 + dj * 16 + l15] =
                f2bf(acc_o[dj][reg] / rsum[reg]);
        }
}

// ---------------------------------------------------------------------------
extern "C" void kernel_launch(void* const* d_in, const int* in_sizes, int n_in,
                              void* d_out, int out_size, void* d_ws, size_t ws_size,
                              hipStream_t stream)
{
    const float* x      = (const float*)d_in[0];
    const float* qkv_w  = (const float*)d_in[1];
    const float* qkv_b  = (const float*)d_in[2];
    const float* out_w  = (const float*)d_in[3];
    const float* out_b  = (const float*)d_in[4];
    const float* rel    = (const float*)d_in[5];
    const float* bn1_g  = (const float*)d_in[6];
    const float* bn1_b  = (const float*)d_in[7];
    const float* bn1_m  = (const float*)d_in[8];
    const float* bn1_v  = (const float*)d_in[9];
    const float* ffn1_w = (const float*)d_in[10];
    const float* ffn1_b = (const float*)d_in[11];
    const float* ffn2_w = (const float*)d_in[12];
    const float* ffn2_b = (const float*)d_in[13];
    const float* bn2_g  = (const float*)d_in[14];
    const float* bn2_b  = (const float*)d_in[15];
    const float* bn2_m  = (const float*)d_in[16];
    const float* bn2_v  = (const float*)d_in[17];

    float* out = (float*)d_out;
    short* ws  = (short*)d_ws;

    size_t off = 0;
    short* qkvw_bf = ws + off; off += (size_t)1536 * 512;
    short* outw_bf = ws + off; off += (size_t)512 * 512;
    short* f1w_bf  = ws + off; off += (size_t)1024 * 512;
    short* f2w_bf  = ws + off; off += (size_t)512 * 1024;
    short* xT      = ws + off; off += (size_t)B_ * 512 * 512;
    short* qkT     = ws + off; off += (size_t)B_ * 512 * 1024;
    short* vTb     = ws + off; off += (size_t)B_ * 512 * 512;
    short* attnT   = ws + off; off += (size_t)B_ * 512 * 512;
    short* h_bf    = ws + off; off += (size_t)B_ * 512 * 512;
    short* f1_bf   = ws + off; off += (size_t)B_ * 512 * 1024;
    float* h_f32   = (float*)(ws + off);   // + B*512*512 floats

    const dim3 blk(256);

    // weight conversions
    cvt_bf16_k<<<dim3((1536 * 512 / 4 + 255) / 256), blk, 0, stream>>>(qkv_w, qkvw_bf, 1536 * 512 / 4);
    cvt_bf16_k<<<dim3((512 * 512 / 4 + 255) / 256), blk, 0, stream>>>(out_w, outw_bf, 512 * 512 / 4);
    cvt_bf16_k<<<dim3((1024 * 512 / 4 + 255) / 256), blk, 0, stream>>>(ffn1_w, f1w_bf, 1024 * 512 / 4);
    cvt_bf16_k<<<dim3((512 * 1024 / 4 + 255) / 256), blk, 0, stream>>>(ffn2_w, f2w_bf, 512 * 1024 / 4);

    // x -> xT bf16
    transpose_x<<<dim3(8, 8, B_), blk, 0, stream>>>(x, xT);

    // 1) qkv projection (q,k -> qkT [n][1024]; v -> vTb [dv][n])
    gemm_mfma<EPI_QKV, 512, 1024><<<dim3(12, 4, B_), blk, 0, stream>>>(
        xT, qkvw_bf, qkv_b, qkT, vTb, nullptr, nullptr, nullptr, nullptr, nullptr, nullptr);

    // 2) attention
    attn_mfma<<<dim3(8, H_, B_), blk, 0, stream>>>(qkT, vTb, rel, attnT);

    // 3) out projection + residual(x) + BN1 -> h_bf + h_f32
    gemm_mfma<EPI_BN1, 512, 512><<<dim3(4, 4, B_), blk, 0, stream>>>(
        attnT, outw_bf, out_b, h_bf, nullptr, h_f32, x, bn1_g, bn1_b, bn1_m, bn1_v);

    // 4) ffn1 + GELU -> f1_bf
    gemm_mfma<EPI_GELU, 512, 1024><<<dim3(8, 4, B_), blk, 0, stream>>>(
        h_bf, f1w_bf, ffn1_b, f1_bf, nullptr, nullptr, nullptr, nullptr, nullptr, nullptr, nullptr);

    // 5) ffn2 + residual(h) + BN2 -> out fp32 [b][c][n]
    gemm_mfma<EPI_BN2, 1024, 512><<<dim3(4, 4, B_), blk, 0, stream>>>(
        f1_bf, f2w_bf, ffn2_b, nullptr, nullptr, out, h_f32, bn2_g, bn2_b, bn2_m, bn2_v);
}